// Round 6
// baseline (925.657 us; speedup 1.0000x reference)
//
#include <hip/hip_runtime.h>

#define N_NODES 100000
#define N_EDGES 1600000
#define DIM 128

#define BK_BITS 7
#define BK_NODES 128
#define NBK ((N_NODES + BK_NODES - 1) / BK_NODES)   // 782
#define BCAP 4096                 // mean 2046/bucket, sd ~45 -> no overflow

typedef __attribute__((ext_vector_type(8))) short bf16x8;
typedef __attribute__((ext_vector_type(4))) float f32x4;

__device__ inline unsigned short f2bf(float f) {
    unsigned u = __builtin_bit_cast(unsigned, f);
    return (unsigned short)((u + 0x7FFFu + ((u >> 16) & 1u)) >> 16);   // RNE
}

// ===========================================================================
// Bucket scatter: packed word (dst_low7<<17)|src appended to dst's bucket.
// Replaces deg+scan+fill: no 100k-wide atomics, writes cluster at 782
// bucket frontiers (L2 line merging).
// ===========================================================================
__global__ __launch_bounds__(256) void bfill_k(const int* __restrict__ ei,
                                               int* __restrict__ bcursor,
                                               int* __restrict__ bbuf)
{
    int e = blockIdx.x * 256 + threadIdx.x;
    if (e >= N_EDGES) return;
    int src = ei[e];
    int dst = ei[N_EDGES + e];
    int b = dst >> BK_BITS;
    int pos = atomicAdd(bcursor + b, 1);
    if (pos < BCAP) bbuf[b * BCAP + pos] = ((dst & (BK_NODES - 1)) << 17) | src;
}

// ===========================================================================
// Per-bucket aggregation: LDS counting-sort into per-node edge lists, then
// R3-style per-wave gather (independent float2 loads, 4-deep MLP).
// a[n] = x[n] + mean over in-neighbors. Degree = histogram count.
// ===========================================================================
__global__ __launch_bounds__(256) void agg_bucket_k(const float* __restrict__ x,
                                                    const int* __restrict__ bcursor,
                                                    const int* __restrict__ bbuf,
                                                    float* __restrict__ a)
{
    __shared__ int elist[BCAP];          // 16 KB sorted src list
    __shared__ int bins[BK_NODES];       // degree histogram
    __shared__ int startp[BK_NODES];     // exclusive prefix
    __shared__ int cur[BK_NODES];
    __shared__ int scanb[BK_NODES];

    const int t = threadIdx.x;
    const int b = blockIdx.x;

    if (t < BK_NODES) bins[t] = 0;
    __syncthreads();

    int n = bcursor[b];
    if (n > BCAP) n = BCAP;
    const int* bp = bbuf + b * BCAP;

    // load bucket words into registers + histogram
    int wreg[BCAP / 256];                // 16
    const int nIter = (n + 255) >> 8;
    #pragma unroll
    for (int i = 0; i < BCAP / 256; ++i) wreg[i] = -1;
    for (int i = 0; i < nIter; ++i) {
        int idx = t + (i << 8);
        if (idx < n) {
            int word = bp[idx];
            wreg[i] = word;
            atomicAdd(&bins[word >> 17], 1);
        }
    }
    __syncthreads();

    // 128-wide exclusive prefix (Hillis-Steele)
    if (t < BK_NODES) scanb[t] = bins[t];
    __syncthreads();
    #pragma unroll
    for (int off = 1; off < BK_NODES; off <<= 1) {
        int add = (t >= off && t < BK_NODES) ? scanb[t - off] : 0;
        __syncthreads();
        if (t < BK_NODES) scanb[t] += add;
        __syncthreads();
    }
    if (t < BK_NODES) {
        startp[t] = scanb[t] - bins[t];
        cur[t] = scanb[t] - bins[t];
    }
    __syncthreads();

    // counting-sort scatter into elist
    for (int i = 0; i < nIter; ++i) {
        int word = wreg[i];
        if (word >= 0) {
            int dl = word >> 17;
            int pos = atomicAdd(&cur[dl], 1);
            elist[pos] = word & 0x1FFFF;
        }
    }
    __syncthreads();

    // per-wave gather: wave handles nodes b*128 + {wv, wv+4, ...}
    const int wv = t >> 6, lane = t & 63;
    for (int i = wv; i < BK_NODES; i += 4) {
        int node = b * BK_NODES + i;
        if (node >= N_NODES) break;
        int beg = startp[i], deg = bins[i], end = beg + deg;
        float ax = 0.f, ay = 0.f;
        int e = beg;
        for (; e + 4 <= end; e += 4) {
            int s0 = elist[e], s1 = elist[e + 1], s2 = elist[e + 2], s3 = elist[e + 3];
            float2 v0 = *(const float2*)(x + s0 * DIM + lane * 2);
            float2 v1 = *(const float2*)(x + s1 * DIM + lane * 2);
            float2 v2 = *(const float2*)(x + s2 * DIM + lane * 2);
            float2 v3 = *(const float2*)(x + s3 * DIM + lane * 2);
            ax += (v0.x + v1.x) + (v2.x + v3.x);
            ay += (v0.y + v1.y) + (v2.y + v3.y);
        }
        for (; e < end; ++e) {
            int s0 = elist[e];
            float2 v0 = *(const float2*)(x + s0 * DIM + lane * 2);
            ax += v0.x; ay += v0.y;
        }
        float inv = 1.0f / fmaxf((float)deg, 1.0f);
        float2 xv = *(const float2*)(x + node * DIM + lane * 2);
        float2 o;
        o.x = xv.x + ax * inv;
        o.y = xv.y + ay * inv;
        *(float2*)(a + node * DIM + lane * 2) = o;
    }
}

// ===========================================================================
// Weight transpose+convert: Wt[n*128+k] = bf16(W[k*128+n]).
// ===========================================================================
__global__ __launch_bounds__(256) void wcvt_k(const float* __restrict__ W,
                                              unsigned short* __restrict__ Wt)
{
    int id = blockIdx.x * 256 + threadIdx.x;      // 16384
    int n = id >> 7, k = id & 127;
    Wt[n * DIM + k] = f2bf(W[k * DIM + n]);
}

// ===========================================================================
// MFMA GEMM1 (R5, unchanged): h1 = A @ W1 + b1 in-place + BN column stats.
// ===========================================================================
__global__ __launch_bounds__(256) void gemm1_mfma_k(
    float* ah, const unsigned short* __restrict__ Wt,
    const float* __restrict__ bias,
    float* __restrict__ colsum, float* __restrict__ colsq)
{
    __shared__ unsigned short Alds[128 * 136];
    __shared__ unsigned short Wlds[128 * 136];
    __shared__ float cstat[256];

    const int t = threadIdx.x;
    const int row0 = blockIdx.x * 128;
    if (t < 256) cstat[t] = 0.f;

    for (int i = t; i < 2048; i += 256) {
        int r = i >> 4, seg = i & 15;
        int gr = row0 + r;
        bf16x8 o;
        if (gr < N_NODES) {
            const float* p = ah + gr * DIM + seg * 8;
            float4 v0 = *(const float4*)p;
            float4 v1 = *(const float4*)(p + 4);
            o[0] = (short)f2bf(v0.x); o[1] = (short)f2bf(v0.y);
            o[2] = (short)f2bf(v0.z); o[3] = (short)f2bf(v0.w);
            o[4] = (short)f2bf(v1.x); o[5] = (short)f2bf(v1.y);
            o[6] = (short)f2bf(v1.z); o[7] = (short)f2bf(v1.w);
        } else {
            o = (bf16x8)(short)0;
        }
        *(bf16x8*)(Alds + r * 136 + seg * 8) = o;
        *(bf16x8*)(Wlds + r * 136 + seg * 8) = *(const bf16x8*)(Wt + r * DIM + seg * 8);
    }
    __syncthreads();

    const int w = t >> 6, lane = t & 63;
    const int m = lane & 15, q = lane >> 4;

    f32x4 acc[2][8];
    #pragma unroll
    for (int i = 0; i < 2; ++i)
        #pragma unroll
        for (int ct = 0; ct < 8; ++ct) acc[i][ct] = (f32x4)0.f;

    #pragma unroll
    for (int kb = 0; kb < DIM; kb += 32) {
        bf16x8 af0 = *(bf16x8*)(Alds + ((w * 2 + 0) * 16 + m) * 136 + kb + q * 8);
        bf16x8 af1 = *(bf16x8*)(Alds + ((w * 2 + 1) * 16 + m) * 136 + kb + q * 8);
        #pragma unroll
        for (int ct = 0; ct < 8; ++ct) {
            bf16x8 bf = *(bf16x8*)(Wlds + (ct * 16 + m) * 136 + kb + q * 8);
            acc[0][ct] = __builtin_amdgcn_mfma_f32_16x16x32_bf16(af0, bf, acc[0][ct], 0, 0, 0);
            acc[1][ct] = __builtin_amdgcn_mfma_f32_16x16x32_bf16(af1, bf, acc[1][ct], 0, 0, 0);
        }
    }

    #pragma unroll
    for (int ct = 0; ct < 8; ++ct) {
        int col = ct * 16 + m;
        float bb = bias[col];
        float ps = 0.f, pq = 0.f;
        #pragma unroll
        for (int i = 0; i < 2; ++i) {
            int rbase = row0 + (w * 2 + i) * 16 + q * 4;
            #pragma unroll
            for (int r = 0; r < 4; ++r) {
                int gr = rbase + r;
                if (gr < N_NODES) {
                    float v = acc[i][ct][r] + bb;
                    ah[gr * DIM + col] = v;
                    ps += v; pq += v * v;
                }
            }
        }
        atomicAdd(&cstat[col], ps);
        atomicAdd(&cstat[128 + col], pq);
    }
    __syncthreads();
    if (t < 128) {
        atomicAdd(colsum + t, cstat[t]);
        atomicAdd(colsq + t, cstat[128 + t]);
    }
}

__global__ void bnstats_k(const float* __restrict__ colsum, const float* __restrict__ colsq,
                          const float* __restrict__ gamma, const float* __restrict__ beta,
                          float* __restrict__ scale, float* __restrict__ shift)
{
    int j = threadIdx.x;
    const float inv_n = 1.0f / (float)N_NODES;
    float mu = colsum[j] * inv_n;
    float var = colsq[j] * inv_n - mu * mu;   // biased variance (torch BN)
    float sc = gamma[j] * rsqrtf(var + 1e-5f);
    scale[j] = sc;
    shift[j] = beta[j] - mu * sc;
}

// ===========================================================================
// MFMA GEMM2 (R5, unchanged): out = [relu]( relu(h1*scale+shift) @ W2 + b2 )
// ===========================================================================
__global__ __launch_bounds__(256) void gemm2_mfma_k(
    const float* __restrict__ h1, const float* __restrict__ scale, const float* __restrict__ shift,
    const unsigned short* __restrict__ Wt, const float* __restrict__ bias,
    float* __restrict__ out, int relu_out)
{
    __shared__ unsigned short Alds[128 * 136];
    __shared__ unsigned short Wlds[128 * 136];
    __shared__ float ssc[256];

    const int t = threadIdx.x;
    const int row0 = blockIdx.x * 128;
    if (t < 128) { ssc[t] = scale[t]; ssc[128 + t] = shift[t]; }
    __syncthreads();

    for (int i = t; i < 2048; i += 256) {
        int r = i >> 4, seg = i & 15;
        int gr = row0 + r;
        bf16x8 o;
        if (gr < N_NODES) {
            const float* p = h1 + gr * DIM + seg * 8;
            float4 v0 = *(const float4*)p;
            float4 v1 = *(const float4*)(p + 4);
            int cb = seg * 8;
            float f[8] = {v0.x, v0.y, v0.z, v0.w, v1.x, v1.y, v1.z, v1.w};
            #pragma unroll
            for (int u = 0; u < 8; ++u) {
                float v = fmaxf(f[u] * ssc[cb + u] + ssc[128 + cb + u], 0.f);
                o[u] = (short)f2bf(v);
            }
        } else {
            o = (bf16x8)(short)0;
        }
        *(bf16x8*)(Alds + r * 136 + seg * 8) = o;
        *(bf16x8*)(Wlds + r * 136 + seg * 8) = *(const bf16x8*)(Wt + r * DIM + seg * 8);
    }
    __syncthreads();

    const int w = t >> 6, lane = t & 63;
    const int m = lane & 15, q = lane >> 4;

    f32x4 acc[2][8];
    #pragma unroll
    for (int i = 0; i < 2; ++i)
        #pragma unroll
        for (int ct = 0; ct < 8; ++ct) acc[i][ct] = (f32x4)0.f;

    #pragma unroll
    for (int kb = 0; kb < DIM; kb += 32) {
        bf16x8 af0 = *(bf16x8*)(Alds + ((w * 2 + 0) * 16 + m) * 136 + kb + q * 8);
        bf16x8 af1 = *(bf16x8*)(Alds + ((w * 2 + 1) * 16 + m) * 136 + kb + q * 8);
        #pragma unroll
        for (int ct = 0; ct < 8; ++ct) {
            bf16x8 bf = *(bf16x8*)(Wlds + (ct * 16 + m) * 136 + kb + q * 8);
            acc[0][ct] = __builtin_amdgcn_mfma_f32_16x16x32_bf16(af0, bf, acc[0][ct], 0, 0, 0);
            acc[1][ct] = __builtin_amdgcn_mfma_f32_16x16x32_bf16(af1, bf, acc[1][ct], 0, 0, 0);
        }
    }

    #pragma unroll
    for (int ct = 0; ct < 8; ++ct) {
        int col = ct * 16 + m;
        float bb = bias[col];
        #pragma unroll
        for (int i = 0; i < 2; ++i) {
            int rbase = row0 + (w * 2 + i) * 16 + q * 4;
            #pragma unroll
            for (int r = 0; r < 4; ++r) {
                int gr = rbase + r;
                if (gr < N_NODES) {
                    float v = acc[i][ct][r] + bb;
                    if (relu_out) v = fmaxf(v, 0.f);
                    out[gr * DIM + col] = v;
                }
            }
        }
    }
}

// ---------------------------------------------------------------------------
// Workspace layout:
//   floats: ah (a/h1 aliased, 12.8M) @ 0; colsum@12.8M, colsq@+128,
//           scale@+256, shift@+384
//   ints (@ ws+12800512, 16B-aligned): bbuf[NBK*BCAP=3,203,072], bcursor[782]
//   ushorts (@ ibase+3204096, 16B-aligned): Wt x4, 16384 each
// Total ≈ 64.3 MB (R1 used 103 MB fine).
// ---------------------------------------------------------------------------
extern "C" void kernel_launch(void* const* d_in, const int* in_sizes, int n_in,
                              void* d_out, int out_size, void* d_ws, size_t ws_size,
                              hipStream_t stream)
{
    const float* x    = (const float*)d_in[0];
    const int*   ei   = (const int*)d_in[1];
    const float* W1_0 = (const float*)d_in[2];
    const float* b1_0 = (const float*)d_in[3];
    const float* g_0  = (const float*)d_in[4];
    const float* be_0 = (const float*)d_in[5];
    const float* W2_0 = (const float*)d_in[6];
    const float* b2_0 = (const float*)d_in[7];
    const float* W1_1 = (const float*)d_in[8];
    const float* b1_1 = (const float*)d_in[9];
    const float* g_1  = (const float*)d_in[10];
    const float* be_1 = (const float*)d_in[11];
    const float* W2_1 = (const float*)d_in[12];
    const float* b2_1 = (const float*)d_in[13];
    float* out = (float*)d_out;
    float* ws  = (float*)d_ws;

    float* ah     = ws;
    float* colsum = ws + 12800000;
    float* colsq  = colsum + 128;
    float* scale  = colsum + 256;
    float* shift  = colsum + 384;
    int* ibase    = (int*)(ws + 12800512);
    int* bbuf     = ibase;
    int* bcursor  = ibase + NBK * BCAP;
    unsigned short* wt10 = (unsigned short*)(ibase + 3204096);
    unsigned short* wt20 = wt10 + 16384;
    unsigned short* wt11 = wt10 + 32768;
    unsigned short* wt21 = wt10 + 49152;

    dim3 blk(256);
    int edge_blocks = (N_EDGES + 255) / 256;           // 6250
    int mfma_blocks = (N_NODES + 127) / 128;           // 782

    // ---- weight convert + bucket build (shared by both layers) ----
    wcvt_k<<<64, blk, 0, stream>>>(W1_0, wt10);
    wcvt_k<<<64, blk, 0, stream>>>(W2_0, wt20);
    wcvt_k<<<64, blk, 0, stream>>>(W1_1, wt11);
    wcvt_k<<<64, blk, 0, stream>>>(W2_1, wt21);
    hipMemsetAsync(bcursor, 0, NBK * sizeof(int), stream);
    bfill_k<<<edge_blocks, blk, 0, stream>>>(ei, bcursor, bbuf);

    // ---- layer 0 ----
    hipMemsetAsync(colsum, 0, 256 * sizeof(float), stream);
    agg_bucket_k<<<NBK, blk, 0, stream>>>(x, bcursor, bbuf, ah);
    gemm1_mfma_k<<<mfma_blocks, blk, 0, stream>>>(ah, wt10, b1_0, colsum, colsq);
    bnstats_k<<<1, 128, 0, stream>>>(colsum, colsq, g_0, be_0, scale, shift);
    gemm2_mfma_k<<<mfma_blocks, blk, 0, stream>>>(ah, scale, shift, wt20, b2_0, out, 1);

    // ---- layer 1 ----
    hipMemsetAsync(colsum, 0, 256 * sizeof(float), stream);
    agg_bucket_k<<<NBK, blk, 0, stream>>>(out, bcursor, bbuf, ah);
    gemm1_mfma_k<<<mfma_blocks, blk, 0, stream>>>(ah, wt11, b1_1, colsum, colsq);
    bnstats_k<<<1, 128, 0, stream>>>(colsum, colsq, g_1, be_1, scale, shift);
    gemm2_mfma_k<<<mfma_blocks, blk, 0, stream>>>(ah, scale, shift, wt21, b2_1, out, 0);
}

// Round 7
// 528.991 us; speedup vs baseline: 1.7499x; 1.7499x over previous
//
#include <hip/hip_runtime.h>

#define N_NODES 100000
#define N_EDGES 1600000
#define DIM 128

#define BK_BITS 7
#define BK_NODES 128
#define NBK ((N_NODES + BK_NODES - 1) / BK_NODES)   // 782
#define BCAP 2688                 // mean 2046/bucket, sd ~45 -> 14 sigma

typedef __attribute__((ext_vector_type(8))) short bf16x8;
typedef __attribute__((ext_vector_type(4))) float f32x4;

__device__ inline unsigned short f2bf(float f) {
    unsigned u = __builtin_bit_cast(unsigned, f);
    return (unsigned short)((u + 0x7FFFu + ((u >> 16) & 1u)) >> 16);   // RNE
}
__device__ inline float bf2f(unsigned short u) {
    unsigned v = ((unsigned)u) << 16;
    return __builtin_bit_cast(float, v);
}

// ===========================================================================
// x -> bf16 (vectorized), once per call
// ===========================================================================
__global__ __launch_bounds__(256) void xcvt_k(const float* __restrict__ x,
                                              unsigned short* __restrict__ xb)
{
    int i = (blockIdx.x * 256 + threadIdx.x) * 4;
    if (i >= N_NODES * DIM) return;
    float4 v = *(const float4*)(x + i);
    unsigned short o[4] = {f2bf(v.x), f2bf(v.y), f2bf(v.z), f2bf(v.w)};
    xb[i] = o[0]; xb[i+1] = o[1]; xb[i+2] = o[2]; xb[i+3] = o[3];
}

// ===========================================================================
// Block-aggregated bucket fill: 8192 edges/block. LDS histogram over 782
// buckets -> ONE global atomic per (block,bucket) range reservation ->
// LDS-cursor scatter (per-block per-bucket runs of ~10 consecutive words).
// Replaces deg+scan+fill; avoids R6's 2050-deep cursor contention.
// ===========================================================================
__global__ __launch_bounds__(512) void bfill2_k(const int* __restrict__ ei,
                                                int* __restrict__ bcursor,
                                                int* __restrict__ bbuf)
{
    __shared__ int hist[NBK];
    __shared__ int cur[NBK];
    const int t = threadIdx.x;
    const int e0 = blockIdx.x * 8192;

    for (int b = t; b < NBK; b += 512) hist[b] = 0;
    __syncthreads();
    #pragma unroll
    for (int i = 0; i < 16; ++i) {
        int e = e0 + i * 512 + t;
        if (e < N_EDGES) atomicAdd(&hist[ei[N_EDGES + e] >> BK_BITS], 1);
    }
    __syncthreads();
    for (int b = t; b < NBK; b += 512) {
        int h = hist[b];
        cur[b] = h ? atomicAdd(bcursor + b, h) : 0;
    }
    __syncthreads();
    #pragma unroll
    for (int i = 0; i < 16; ++i) {
        int e = e0 + i * 512 + t;
        if (e < N_EDGES) {
            int src = ei[e];
            int dst = ei[N_EDGES + e];
            int b = dst >> BK_BITS;
            int pos = atomicAdd(&cur[b], 1);
            if (pos < BCAP) bbuf[b * BCAP + pos] = ((dst & (BK_NODES - 1)) << 17) | src;
        }
    }
}

// ===========================================================================
// Per-bucket aggregation (bf16 features): LDS counting-sort into per-node
// edge lists, then R3-style per-wave gather (independent ushort2 loads).
// ab[n] = bf16( x[n] + mean over in-neighbors ), fp32 accumulate.
// ===========================================================================
__global__ __launch_bounds__(256) void agg_bucket_k(const unsigned short* __restrict__ xb,
                                                    const int* __restrict__ bcursor,
                                                    const int* __restrict__ bbuf,
                                                    unsigned short* __restrict__ ab)
{
    __shared__ int elist[BCAP];
    __shared__ int bins[BK_NODES];
    __shared__ int startp[BK_NODES];
    __shared__ int cur[BK_NODES];
    __shared__ int scanb[BK_NODES];

    const int t = threadIdx.x;
    const int b = blockIdx.x;

    if (t < BK_NODES) bins[t] = 0;
    __syncthreads();

    int n = bcursor[b];
    if (n > BCAP) n = BCAP;
    const int* bp = bbuf + b * BCAP;

    int wreg[(BCAP + 255) / 256];                 // 11
    const int nIter = (n + 255) >> 8;
    #pragma unroll
    for (int i = 0; i < (BCAP + 255) / 256; ++i) wreg[i] = -1;
    for (int i = 0; i < nIter; ++i) {
        int idx = t + (i << 8);
        if (idx < n) {
            int word = bp[idx];
            wreg[i] = word;
            atomicAdd(&bins[word >> 17], 1);
        }
    }
    __syncthreads();

    if (t < BK_NODES) scanb[t] = bins[t];
    __syncthreads();
    #pragma unroll
    for (int off = 1; off < BK_NODES; off <<= 1) {
        int add = (t >= off && t < BK_NODES) ? scanb[t - off] : 0;
        __syncthreads();
        if (t < BK_NODES) scanb[t] += add;
        __syncthreads();
    }
    if (t < BK_NODES) {
        startp[t] = scanb[t] - bins[t];
        cur[t] = scanb[t] - bins[t];
    }
    __syncthreads();

    for (int i = 0; i < nIter; ++i) {
        int word = wreg[i];
        if (word >= 0) {
            int dl = word >> 17;
            int pos = atomicAdd(&cur[dl], 1);
            elist[pos] = word & 0x1FFFF;
        }
    }
    __syncthreads();

    const int wv = t >> 6, lane = t & 63;
    for (int i = wv; i < BK_NODES; i += 4) {
        int node = b * BK_NODES + i;
        if (node >= N_NODES) break;
        int beg = startp[i], deg = bins[i], end = beg + deg;
        float ax = 0.f, ay = 0.f;
        int e = beg;
        for (; e + 4 <= end; e += 4) {
            int s0 = elist[e], s1 = elist[e + 1], s2 = elist[e + 2], s3 = elist[e + 3];
            ushort2 v0 = *(const ushort2*)(xb + s0 * DIM + lane * 2);
            ushort2 v1 = *(const ushort2*)(xb + s1 * DIM + lane * 2);
            ushort2 v2 = *(const ushort2*)(xb + s2 * DIM + lane * 2);
            ushort2 v3 = *(const ushort2*)(xb + s3 * DIM + lane * 2);
            ax += (bf2f(v0.x) + bf2f(v1.x)) + (bf2f(v2.x) + bf2f(v3.x));
            ay += (bf2f(v0.y) + bf2f(v1.y)) + (bf2f(v2.y) + bf2f(v3.y));
        }
        for (; e < end; ++e) {
            int s0 = elist[e];
            ushort2 v0 = *(const ushort2*)(xb + s0 * DIM + lane * 2);
            ax += bf2f(v0.x); ay += bf2f(v0.y);
        }
        float inv = 1.0f / fmaxf((float)deg, 1.0f);
        ushort2 xv = *(const ushort2*)(xb + node * DIM + lane * 2);
        ushort2 o;
        o.x = f2bf(bf2f(xv.x) + ax * inv);
        o.y = f2bf(bf2f(xv.y) + ay * inv);
        *(ushort2*)(ab + node * DIM + lane * 2) = o;
    }
}

// ===========================================================================
// Weight transpose+convert: Wt[n*128+k] = bf16(W[k*128+n]).
// ===========================================================================
__global__ __launch_bounds__(256) void wcvt_k(const float* __restrict__ W,
                                              unsigned short* __restrict__ Wt)
{
    int id = blockIdx.x * 256 + threadIdx.x;      // 16384
    int n = id >> 7, k = id & 127;
    Wt[n * DIM + k] = f2bf(W[k * DIM + n]);
}

// ===========================================================================
// MFMA GEMM1: h1(fp32) = A(bf16) @ W1 + b1, + fused BN column stats.
// A staging is now a pure bf16 copy (no conversion).
// ===========================================================================
__global__ __launch_bounds__(256) void gemm1_mfma_k(
    const unsigned short* __restrict__ ab, float* __restrict__ h1,
    const unsigned short* __restrict__ Wt, const float* __restrict__ bias,
    float* __restrict__ colsum, float* __restrict__ colsq)
{
    __shared__ unsigned short Alds[128 * 136];
    __shared__ unsigned short Wlds[128 * 136];
    __shared__ float cstat[256];

    const int t = threadIdx.x;
    const int row0 = blockIdx.x * 128;
    if (t < 256) cstat[t] = 0.f;

    for (int i = t; i < 2048; i += 256) {
        int r = i >> 4, seg = i & 15;
        int gr = row0 + r;
        bf16x8 o = (gr < N_NODES) ? *(const bf16x8*)(ab + gr * DIM + seg * 8)
                                  : (bf16x8)(short)0;
        *(bf16x8*)(Alds + r * 136 + seg * 8) = o;
        *(bf16x8*)(Wlds + r * 136 + seg * 8) = *(const bf16x8*)(Wt + r * DIM + seg * 8);
    }
    __syncthreads();

    const int w = t >> 6, lane = t & 63;
    const int m = lane & 15, q = lane >> 4;

    f32x4 acc[2][8];
    #pragma unroll
    for (int i = 0; i < 2; ++i)
        #pragma unroll
        for (int ct = 0; ct < 8; ++ct) acc[i][ct] = (f32x4)0.f;

    #pragma unroll
    for (int kb = 0; kb < DIM; kb += 32) {
        bf16x8 af0 = *(bf16x8*)(Alds + ((w * 2 + 0) * 16 + m) * 136 + kb + q * 8);
        bf16x8 af1 = *(bf16x8*)(Alds + ((w * 2 + 1) * 16 + m) * 136 + kb + q * 8);
        #pragma unroll
        for (int ct = 0; ct < 8; ++ct) {
            bf16x8 bf = *(bf16x8*)(Wlds + (ct * 16 + m) * 136 + kb + q * 8);
            acc[0][ct] = __builtin_amdgcn_mfma_f32_16x16x32_bf16(af0, bf, acc[0][ct], 0, 0, 0);
            acc[1][ct] = __builtin_amdgcn_mfma_f32_16x16x32_bf16(af1, bf, acc[1][ct], 0, 0, 0);
        }
    }

    #pragma unroll
    for (int ct = 0; ct < 8; ++ct) {
        int col = ct * 16 + m;
        float bb = bias[col];
        float ps = 0.f, pq = 0.f;
        #pragma unroll
        for (int i = 0; i < 2; ++i) {
            int rbase = row0 + (w * 2 + i) * 16 + q * 4;
            #pragma unroll
            for (int r = 0; r < 4; ++r) {
                int gr = rbase + r;
                if (gr < N_NODES) {
                    float v = acc[i][ct][r] + bb;
                    h1[gr * DIM + col] = v;
                    ps += v; pq += v * v;
                }
            }
        }
        atomicAdd(&cstat[col], ps);
        atomicAdd(&cstat[128 + col], pq);
    }
    __syncthreads();
    if (t < 128) {
        atomicAdd(colsum + t, cstat[t]);
        atomicAdd(colsq + t, cstat[128 + t]);
    }
}

__global__ void bnstats_k(const float* __restrict__ colsum, const float* __restrict__ colsq,
                          const float* __restrict__ gamma, const float* __restrict__ beta,
                          float* __restrict__ scale, float* __restrict__ shift)
{
    int j = threadIdx.x;
    const float inv_n = 1.0f / (float)N_NODES;
    float mu = colsum[j] * inv_n;
    float var = colsq[j] * inv_n - mu * mu;   // biased variance (torch BN)
    float sc = gamma[j] * rsqrtf(var + 1e-5f);
    scale[j] = sc;
    shift[j] = beta[j] - mu * sc;
}

// ===========================================================================
// MFMA GEMM2: t = relu(h1*scale+shift); r = t @ W2 + b2.
// mode 1: write bf16 relu(r) -> xbout (inter-layer activation)
// mode 0: write fp32 r -> outf (final output)
// ===========================================================================
__global__ __launch_bounds__(256) void gemm2_mfma_k(
    const float* __restrict__ h1, const float* __restrict__ scale, const float* __restrict__ shift,
    const unsigned short* __restrict__ Wt, const float* __restrict__ bias,
    float* __restrict__ outf, unsigned short* __restrict__ xbout, int mode)
{
    __shared__ unsigned short Alds[128 * 136];
    __shared__ unsigned short Wlds[128 * 136];
    __shared__ float ssc[256];

    const int t = threadIdx.x;
    const int row0 = blockIdx.x * 128;
    if (t < 128) { ssc[t] = scale[t]; ssc[128 + t] = shift[t]; }
    __syncthreads();

    for (int i = t; i < 2048; i += 256) {
        int r = i >> 4, seg = i & 15;
        int gr = row0 + r;
        bf16x8 o;
        if (gr < N_NODES) {
            const float* p = h1 + gr * DIM + seg * 8;
            float4 v0 = *(const float4*)p;
            float4 v1 = *(const float4*)(p + 4);
            int cb = seg * 8;
            float f[8] = {v0.x, v0.y, v0.z, v0.w, v1.x, v1.y, v1.z, v1.w};
            #pragma unroll
            for (int u = 0; u < 8; ++u) {
                float v = fmaxf(f[u] * ssc[cb + u] + ssc[128 + cb + u], 0.f);
                o[u] = (short)f2bf(v);
            }
        } else {
            o = (bf16x8)(short)0;
        }
        *(bf16x8*)(Alds + r * 136 + seg * 8) = o;
        *(bf16x8*)(Wlds + r * 136 + seg * 8) = *(const bf16x8*)(Wt + r * DIM + seg * 8);
    }
    __syncthreads();

    const int w = t >> 6, lane = t & 63;
    const int m = lane & 15, q = lane >> 4;

    f32x4 acc[2][8];
    #pragma unroll
    for (int i = 0; i < 2; ++i)
        #pragma unroll
        for (int ct = 0; ct < 8; ++ct) acc[i][ct] = (f32x4)0.f;

    #pragma unroll
    for (int kb = 0; kb < DIM; kb += 32) {
        bf16x8 af0 = *(bf16x8*)(Alds + ((w * 2 + 0) * 16 + m) * 136 + kb + q * 8);
        bf16x8 af1 = *(bf16x8*)(Alds + ((w * 2 + 1) * 16 + m) * 136 + kb + q * 8);
        #pragma unroll
        for (int ct = 0; ct < 8; ++ct) {
            bf16x8 bf = *(bf16x8*)(Wlds + (ct * 16 + m) * 136 + kb + q * 8);
            acc[0][ct] = __builtin_amdgcn_mfma_f32_16x16x32_bf16(af0, bf, acc[0][ct], 0, 0, 0);
            acc[1][ct] = __builtin_amdgcn_mfma_f32_16x16x32_bf16(af1, bf, acc[1][ct], 0, 0, 0);
        }
    }

    #pragma unroll
    for (int ct = 0; ct < 8; ++ct) {
        int col = ct * 16 + m;
        float bb = bias[col];
        #pragma unroll
        for (int i = 0; i < 2; ++i) {
            int rbase = row0 + (w * 2 + i) * 16 + q * 4;
            #pragma unroll
            for (int r = 0; r < 4; ++r) {
                int gr = rbase + r;
                if (gr < N_NODES) {
                    float v = acc[i][ct][r] + bb;
                    if (mode) xbout[gr * DIM + col] = f2bf(fmaxf(v, 0.f));
                    else      outf[gr * DIM + col] = v;
                }
            }
        }
    }
}

// ---------------------------------------------------------------------------
// Workspace (float units):
//   h1     @ 0          : 12,800,000 fp32
//   colsum @ 12,800,000 : +128 colsq, +256 scale, +384 shift (512)
//   xb     @ 12,800,512 : 12.8M ushort (6.4M floats)  [x_bf16 / interlayer]
//   ab     @ 19,200,512 : 12.8M ushort (6.4M floats)  [agg output]
//   ints   @ 25,600,512 : bbuf[NBK*BCAP=2,102,016], bcursor[782]
//   ushorts after      : Wt x4 (16384 each)
// Total ≈ 111 MB.
// ---------------------------------------------------------------------------
extern "C" void kernel_launch(void* const* d_in, const int* in_sizes, int n_in,
                              void* d_out, int out_size, void* d_ws, size_t ws_size,
                              hipStream_t stream)
{
    const float* x    = (const float*)d_in[0];
    const int*   ei   = (const int*)d_in[1];
    const float* W1_0 = (const float*)d_in[2];
    const float* b1_0 = (const float*)d_in[3];
    const float* g_0  = (const float*)d_in[4];
    const float* be_0 = (const float*)d_in[5];
    const float* W2_0 = (const float*)d_in[6];
    const float* b2_0 = (const float*)d_in[7];
    const float* W1_1 = (const float*)d_in[8];
    const float* b1_1 = (const float*)d_in[9];
    const float* g_1  = (const float*)d_in[10];
    const float* be_1 = (const float*)d_in[11];
    const float* W2_1 = (const float*)d_in[12];
    const float* b2_1 = (const float*)d_in[13];
    float* out = (float*)d_out;
    float* ws  = (float*)d_ws;

    float* h1     = ws;
    float* colsum = ws + 12800000;
    float* colsq  = colsum + 128;
    float* scale  = colsum + 256;
    float* shift  = colsum + 384;
    unsigned short* xb = (unsigned short*)(ws + 12800512);
    unsigned short* ab = (unsigned short*)(ws + 19200512);
    int* ibase    = (int*)(ws + 25600512);
    int* bbuf     = ibase;
    int* bcursor  = ibase + NBK * BCAP;
    unsigned short* wt10 = (unsigned short*)(bcursor + NBK + 2);
    unsigned short* wt20 = wt10 + 16384;
    unsigned short* wt11 = wt10 + 32768;
    unsigned short* wt21 = wt10 + 49152;

    dim3 blk(256);
    int mfma_blocks = (N_NODES + 127) / 128;           // 782
    int fill_blocks = (N_EDGES + 8191) / 8192;         // 196

    // ---- one-time converts + bucket build ----
    xcvt_k<<<(N_NODES * DIM / 4 + 255) / 256, blk, 0, stream>>>(x, xb);
    wcvt_k<<<64, blk, 0, stream>>>(W1_0, wt10);
    wcvt_k<<<64, blk, 0, stream>>>(W2_0, wt20);
    wcvt_k<<<64, blk, 0, stream>>>(W1_1, wt11);
    wcvt_k<<<64, blk, 0, stream>>>(W2_1, wt21);
    hipMemsetAsync(bcursor, 0, NBK * sizeof(int), stream);
    bfill2_k<<<fill_blocks, 512, 0, stream>>>(ei, bcursor, bbuf);

    // ---- layer 0 ----
    hipMemsetAsync(colsum, 0, 256 * sizeof(float), stream);
    agg_bucket_k<<<NBK, blk, 0, stream>>>(xb, bcursor, bbuf, ab);
    gemm1_mfma_k<<<mfma_blocks, blk, 0, stream>>>(ab, h1, wt10, b1_0, colsum, colsq);
    bnstats_k<<<1, 128, 0, stream>>>(colsum, colsq, g_0, be_0, scale, shift);
    gemm2_mfma_k<<<mfma_blocks, blk, 0, stream>>>(h1, scale, shift, wt20, b2_0, nullptr, xb, 1);

    // ---- layer 1 ----
    hipMemsetAsync(colsum, 0, 256 * sizeof(float), stream);
    agg_bucket_k<<<NBK, blk, 0, stream>>>(xb, bcursor, bbuf, ab);
    gemm1_mfma_k<<<mfma_blocks, blk, 0, stream>>>(ab, h1, wt11, b1_1, colsum, colsq);
    bnstats_k<<<1, 128, 0, stream>>>(colsum, colsq, g_1, be_1, scale, shift);
    gemm2_mfma_k<<<mfma_blocks, blk, 0, stream>>>(h1, scale, shift, wt21, b2_1, out, nullptr, 0);
}